// Round 12
// baseline (172.765 us; speedup 1.0000x reference)
//
#include <hip/hip_runtime.h>
#include <hip/hip_bf16.h>

#define B_SZ 8192
#define IH   2048
#define H_SZ 1024
#define BMR  128            // rows per block
#define BK   32             // K per tile
#define NKT  (IH / BK)      // 64 K-tiles
#define BUFB 24576          // one buf: A [128][64B] (8 KiB) + W [256][64B] (16 KiB)
#define WOF2 8192           // W offset inside a buf

typedef __attribute__((ext_vector_type(8))) short  short8;
typedef __attribute__((ext_vector_type(4))) float  floatx4;

static __device__ __forceinline__ ushort f2bf(float f) {
  union { float f; unsigned u; } v; v.f = f;
  unsigned u = v.u;
  u += 0x7fffu + ((u >> 16) & 1u);   // RNE
  return (ushort)(u >> 16);
}
static __device__ __forceinline__ float sigmoidf_(float x) {
  return 1.0f / (1.0f + __expf(-x));
}
static __device__ __forceinline__ float tanhf_(float x) {
  float ax = fabsf(x);
  float e = __expf(-2.0f * ax);
  float t = (1.0f - e) / (1.0f + e);
  return copysignf(t, x);
}
static __device__ __forceinline__ void gload_lds16(const void* gsrc, void* ldst) {
  __builtin_amdgcn_global_load_lds(
      (__attribute__((address_space(1))) const void*)gsrc,
      (__attribute__((address_space(3))) void*)ldst, 16, 0, 0);
}

// ---------------------------------------------------------------------------
// Pre-pass 1: W[k][n] fp32 -> Wt[g][n][k] bf16 (K-contiguous for MFMA B-frag)
// ---------------------------------------------------------------------------
__global__ __launch_bounds__(256) void convert_w_kernel(
    const float* __restrict__ Wf, const float* __restrict__ Wi,
    const float* __restrict__ Wo, const float* __restrict__ Wc,
    ushort* __restrict__ Wt) {
  __shared__ float tile[64][65];
  const int g  = blockIdx.z;
  const float* W = (g == 0) ? Wf : (g == 1) ? Wi : (g == 2) ? Wo : Wc;
  const int n0 = blockIdx.x * 64;
  const int k0 = blockIdx.y * 64;
  const int tid = threadIdx.x;
#pragma unroll
  for (int i = 0; i < 4; ++i) {
    int c = i * 256 + tid;
    int r = c >> 4, c4 = c & 15;
    float4 v = *(const float4*)(W + (size_t)(k0 + r) * H_SZ + n0 + c4 * 4);
    tile[r][c4 * 4 + 0] = v.x;
    tile[r][c4 * 4 + 1] = v.y;
    tile[r][c4 * 4 + 2] = v.z;
    tile[r][c4 * 4 + 3] = v.w;
  }
  __syncthreads();
  const int n  = tid >> 2;
  const int kc = (tid & 3) * 16;
  ushort o[16] __attribute__((aligned(16)));
#pragma unroll
  for (int e = 0; e < 16; ++e) o[e] = f2bf(tile[kc + e][n]);
  ushort* dst = Wt + ((size_t)g * H_SZ + n0 + n) * IH + k0 + kc;
  *(uint4*)(dst)     = *(uint4*)&o[0];
  *(uint4*)(dst + 8) = *(uint4*)&o[8];
}

// ---------------------------------------------------------------------------
// Pre-pass 2: A = [x | h_prev] fp32 -> Abf[8192][2048] bf16
// ---------------------------------------------------------------------------
__global__ __launch_bounds__(256) void convert_a_kernel(
    const float* __restrict__ x, const float* __restrict__ hp,
    ushort* __restrict__ Abf) {
  size_t idx = ((size_t)blockIdx.x * 256 + threadIdx.x) * 8;
  size_t row = idx >> 11;
  size_t col = idx & 2047;
  const float* src = (col < 1024) ? (x  + row * 1024 + col)
                                  : (hp + row * 1024 + (col - 1024));
  float4 v0 = *(const float4*)(src);
  float4 v1 = *(const float4*)(src + 4);
  ushort o[8] __attribute__((aligned(16)));
  o[0] = f2bf(v0.x); o[1] = f2bf(v0.y); o[2] = f2bf(v0.z); o[3] = f2bf(v0.w);
  o[4] = f2bf(v1.x); o[5] = f2bf(v1.y); o[6] = f2bf(v1.z); o[7] = f2bf(v1.w);
  *(uint4*)(Abf + idx) = *(uint4*)&o[0];
}

// ---------------------------------------------------------------------------
// Fused 4-gate GEMM + LSTM epilogue — TWO-BLOCKS-PER-CU structure.
//
// Block: 128 rows x 256 fused cols (4 gates x 64); 4 waves = 2M x 2N;
// per-wave 64 rows x (4 gates x 32 cols): acc[4 mf][8 j], j = 2*gate+ns.
// BK=32 -> LDS/block = 2 bufs x (A 8 KiB + W 16 KiB) = 48 KiB ->
// 2 independent blocks (barrier groups) co-resident per CU at 2 waves/EU
// (256-VGPR cap; demand ~200). When one block drains vmcnt/barrier, the
// sibling's waves feed the MFMA and LDS pipes (m114 overlap mechanism) —
// attacks the measured MFMA/LDS serialization of the 1-block structure.
//
// LDS layout (per buf d at d*24576): A[row 0..127][4 slots x 16B],
// W at +8192 [nrt 0..255][4 slots]. Slot swizzle: LDS slot sl holds global
// k-group sl ^ ((row>>1)&3) (involution; 2-way max bank aliasing = free).
// Applied on global SOURCE (write side, rule 21) and folded into the
// per-thread read base (read side). mf/gate/ns deltas are +16n rows ->
// (row>>1)&3 invariant -> pure immediate offsets on ds_read.
//
// K-loop (2-phase per K-tile, ping-pong bufs):
//   iter t: issue 6 gloads (tile t+1 -> other buf); ds_read 12 b128 (cur);
//           32 MFMA; vmcnt(0); s_barrier.
// WAR: other buf last read in iter t-1; those ds_reads retired before their
//   consuming MFMAs (compiler lgkm waits) hence before BAR(t-1); stage
//   issues after BAR(t-1). RAW: vmcnt(0)+BAR at end of t lands tile t+1
//   before its reads in t+1. Tail stage wraps (&63): dead data. A/W regions
//   in the same buf are disjoint (A 0-8K, W 8K-24K).
// ---------------------------------------------------------------------------
__global__ __launch_bounds__(256, 2) void lstm_fused_kernel(
    const float* __restrict__ Cp, const ushort* __restrict__ Wt,
    const ushort* __restrict__ Abf,
    const float* __restrict__ bf_, const float* __restrict__ bi_,
    const float* __restrict__ bo_, const float* __restrict__ bc_,
    float* __restrict__ out) {
  __shared__ char lds[2 * BUFB];   // 48 KiB

  const int bid = blockIdx.x;
  const int wg  = (bid & 7) * 128 + (bid >> 3);  // bijective, 1024 % 8 == 0
  const int b0  = (wg >> 4) * BMR;               // 64 M-tiles
  const int n0g = (wg & 15) * 64;                // 16 N-tiles (64 cols/gate)

  const int tid = threadIdx.x;
  const int ln  = tid & 63;
  const int wv  = tid >> 6;                      // 4 waves
  const int wm  = wv >> 1, wn = wv & 1;

  floatx4 acc[4][8];
#pragma unroll
  for (int m = 0; m < 4; ++m)
#pragma unroll
    for (int j = 0; j < 8; ++j) acc[m][j] = {0.f, 0.f, 0.f, 0.f};

  // ---- read bases (slot swizzle folded in; deltas are immediates) ----
  const int q  = ((ln & 15) >> 1) & 3;           // (row>>1)&3, +16-row invariant
  const int sx = ((ln >> 4) ^ q) << 4;           // swizzled slot byte
  const int aB = (wm * 64 + (ln & 15)) * 64 + sx;            // + mf*1024
  const int bB = WOF2 + (wn * 32 + (ln & 15)) * 64 + sx;     // + g*4096 + ns*1024

  // ---- stage constants ----
  // slot s = i*256+tid -> row = i*64 + (tid>>2), sl = tid&3,
  // global k-group kg = sl ^ ((row>>1)&3) = (tid&3) ^ ((tid>>3)&3).
  const unsigned kg  = ((unsigned)(tid & 3)) ^ ((unsigned)(tid >> 3) & 3);
  const char* AbfB = (const char*)Abf;
  const char* WtB  = (const char*)Wt;
  unsigned aoff[2], woff[4];
#pragma unroll
  for (int i = 0; i < 2; ++i)
    aoff[i] = (unsigned)(b0 + i * 64 + (tid >> 2)) * 4096u + kg * 16u;
#pragma unroll
  for (int i = 0; i < 4; ++i)     // gate = i, nloc = tid>>2
    woff[i] = (unsigned)(i * 1024 + n0g + (tid >> 2)) * 4096u + kg * 16u;
  const int dstw = wv * 1024;     // wave-uniform part of LDS dest (lane adds 16)

#define SAB(db, ktb)                                                          \
  do {                                                                        \
    gload_lds16(AbfB + (aoff[0] + (unsigned)(ktb)), lds + (db) + dstw);       \
    gload_lds16(AbfB + (aoff[1] + (unsigned)(ktb)), lds + (db) + 4096 + dstw);\
    gload_lds16(WtB  + (woff[0] + (unsigned)(ktb)), lds + (db) + WOF2 + dstw);\
    gload_lds16(WtB  + (woff[1] + (unsigned)(ktb)), lds + (db) + WOF2 + 4096 + dstw);\
    gload_lds16(WtB  + (woff[2] + (unsigned)(ktb)), lds + (db) + WOF2 + 8192 + dstw);\
    gload_lds16(WtB  + (woff[3] + (unsigned)(ktb)), lds + (db) + WOF2 + 12288 + dstw);\
  } while (0)

  short8 aF[4];
  short8 bF[8];
#define RD_A(db, mf)  (aF[mf] = *(const short8*)(lds + (db) + aB + (mf) * 1024))
#define RD_B(db, j)   (bF[j]  = *(const short8*)(lds + (db) + bB +            \
                                 ((j) >> 1) * 4096 + ((j) & 1) * 1024))
#define MFALL()                                                               \
  do {                                                                        \
    __builtin_amdgcn_s_setprio(1);                                            \
    _Pragma("unroll")                                                         \
    for (int mf_ = 0; mf_ < 4; ++mf_)                                         \
      _Pragma("unroll")                                                       \
      for (int j_ = 0; j_ < 8; ++j_)                                          \
        acc[mf_][j_] = __builtin_amdgcn_mfma_f32_16x16x32_bf16(               \
            aF[mf_], bF[j_], acc[mf_][j_], 0, 0, 0);                          \
    __builtin_amdgcn_s_setprio(0);                                            \
  } while (0)
#define BAR   __builtin_amdgcn_s_barrier()
#define VMC0  asm volatile("s_waitcnt vmcnt(0)" ::: "memory")

#define KTILE(db, nb, ktn)                                                    \
  do {                                                                        \
    SAB(nb, ((ktn) & 63) * 64);                                               \
    RD_A(db, 0); RD_A(db, 1); RD_A(db, 2); RD_A(db, 3);                       \
    RD_B(db, 0); RD_B(db, 1); RD_B(db, 2); RD_B(db, 3);                       \
    RD_B(db, 4); RD_B(db, 5); RD_B(db, 6); RD_B(db, 7);                       \
    MFALL();                                                                  \
    VMC0; BAR;                                                                \
  } while (0)

  // ---- prologue: tile 0 -> buf0 ----
  SAB(0, 0);
  VMC0; BAR;

#pragma unroll 1
  for (int it = 0; it < NKT / 2; ++it) {
    KTILE(0,    BUFB, 2 * it + 1);   // tile 2it   in buf0; stage 2it+1 -> buf1
    KTILE(BUFB, 0,    2 * it + 2);   // tile 2it+1 in buf1; stage 2it+2 -> buf0
  }

  // ---- epilogue: gate g at acc[mf][2g+ns]; same lane/reg across gates ----
  const int colq = ln & 15;
  const int rq   = ln >> 4;
  float* outh = out;
  float* outC = out + (size_t)B_SZ * H_SZ;
#pragma unroll
  for (int mf = 0; mf < 4; ++mf) {
#pragma unroll
    for (int ns = 0; ns < 2; ++ns) {
      int n = n0g + wn * 32 + ns * 16 + colq;
      float vbf = bf_[n], vbi = bi_[n], vbo = bo_[n], vbc = bc_[n];
#pragma unroll
      for (int r = 0; r < 4; ++r) {
        int row = b0 + wm * 64 + mf * 16 + rq * 4 + r;
        float fg = sigmoidf_(acc[mf][0 + ns][r] + vbf);
        float ig = sigmoidf_(acc[mf][2 + ns][r] + vbi);
        float og = sigmoidf_(acc[mf][4 + ns][r] + vbo);
        float cg = tanhf_  (acc[mf][6 + ns][r] + vbc);
        float cp = Cp[(size_t)row * H_SZ + n];
        float Ct = fg * cp + ig * cg;
        float ht = og * tanhf_(Ct);
        outh[(size_t)row * H_SZ + n] = ht;
        outC[(size_t)row * H_SZ + n] = Ct;
      }
    }
  }
#undef SAB
#undef RD_A
#undef RD_B
#undef MFALL
#undef BAR
#undef VMC0
#undef KTILE
}

extern "C" void kernel_launch(void* const* d_in, const int* in_sizes, int n_in,
                              void* d_out, int out_size, void* d_ws, size_t ws_size,
                              hipStream_t stream) {
  const float* x  = (const float*)d_in[0];
  const float* hp = (const float*)d_in[1];
  const float* Cp = (const float*)d_in[2];
  const float* Wf = (const float*)d_in[3];
  const float* bf = (const float*)d_in[4];
  const float* Wi = (const float*)d_in[5];
  const float* bi = (const float*)d_in[6];
  const float* Wc = (const float*)d_in[7];
  const float* bc = (const float*)d_in[8];
  const float* Wo = (const float*)d_in[9];
  const float* bo = (const float*)d_in[10];

  ushort* Wt  = (ushort*)d_ws;                           // 16 MiB
  ushort* Abf = (ushort*)((char*)d_ws + (16u << 20));    // 32 MiB

  dim3 gridT(16, 32, 4);
  convert_w_kernel<<<gridT, 256, 0, stream>>>(Wf, Wi, Wo, Wc, Wt);
  convert_a_kernel<<<8192, 256, 0, stream>>>(x, hp, Abf);

  lstm_fused_kernel<<<1024, 256, 0, stream>>>(Cp, Wt, Abf,
                                              bf, bi, bo, bc, (float*)d_out);
}

// Round 13
// 163.826 us; speedup vs baseline: 1.0546x; 1.0546x over previous
//
#include <hip/hip_runtime.h>
#include <hip/hip_bf16.h>

#define B_SZ 8192
#define IH   2048
#define H_SZ 1024
#define BM   256            // rows per block
#define BK   32             // K per tile
#define NKT  (IH / BK)      // 64 K-tiles
#define DB2  32768          // one dbuf: A [256][64B] (16K) + W [256][64B] (16K)
#define WOF  16384          // W offset inside a dbuf

typedef __attribute__((ext_vector_type(8))) short  short8;
typedef __attribute__((ext_vector_type(4))) float  floatx4;

static __device__ __forceinline__ ushort f2bf(float f) {
  union { float f; unsigned u; } v; v.f = f;
  unsigned u = v.u;
  u += 0x7fffu + ((u >> 16) & 1u);   // RNE
  return (ushort)(u >> 16);
}
static __device__ __forceinline__ float sigmoidf_(float x) {
  return 1.0f / (1.0f + __expf(-x));
}
static __device__ __forceinline__ float tanhf_(float x) {
  float ax = fabsf(x);
  float e = __expf(-2.0f * ax);
  float t = (1.0f - e) / (1.0f + e);
  return copysignf(t, x);
}
static __device__ __forceinline__ void gload_lds16(const void* gsrc, void* ldst) {
  __builtin_amdgcn_global_load_lds(
      (__attribute__((address_space(1))) const void*)gsrc,
      (__attribute__((address_space(3))) void*)ldst, 16, 0, 0);
}

// ---------------------------------------------------------------------------
// Pre-pass 1: W[k][n] fp32 -> Wt[g][n][k] bf16 (K-contiguous for MFMA B-frag)
// ---------------------------------------------------------------------------
__global__ __launch_bounds__(256) void convert_w_kernel(
    const float* __restrict__ Wf, const float* __restrict__ Wi,
    const float* __restrict__ Wo, const float* __restrict__ Wc,
    ushort* __restrict__ Wt) {
  __shared__ float tile[64][65];
  const int g  = blockIdx.z;
  const float* W = (g == 0) ? Wf : (g == 1) ? Wi : (g == 2) ? Wo : Wc;
  const int n0 = blockIdx.x * 64;
  const int k0 = blockIdx.y * 64;
  const int tid = threadIdx.x;
#pragma unroll
  for (int i = 0; i < 4; ++i) {
    int c = i * 256 + tid;
    int r = c >> 4, c4 = c & 15;
    float4 v = *(const float4*)(W + (size_t)(k0 + r) * H_SZ + n0 + c4 * 4);
    tile[r][c4 * 4 + 0] = v.x;
    tile[r][c4 * 4 + 1] = v.y;
    tile[r][c4 * 4 + 2] = v.z;
    tile[r][c4 * 4 + 3] = v.w;
  }
  __syncthreads();
  const int n  = tid >> 2;
  const int kc = (tid & 3) * 16;
  ushort o[16] __attribute__((aligned(16)));
#pragma unroll
  for (int e = 0; e < 16; ++e) o[e] = f2bf(tile[kc + e][n]);
  ushort* dst = Wt + ((size_t)g * H_SZ + n0 + n) * IH + k0 + kc;
  *(uint4*)(dst)     = *(uint4*)&o[0];
  *(uint4*)(dst + 8) = *(uint4*)&o[8];
}

// ---------------------------------------------------------------------------
// Pre-pass 2: A = [x | h_prev] fp32 -> Abf[8192][2048] bf16
// ---------------------------------------------------------------------------
__global__ __launch_bounds__(256) void convert_a_kernel(
    const float* __restrict__ x, const float* __restrict__ hp,
    ushort* __restrict__ Abf) {
  size_t idx = ((size_t)blockIdx.x * 256 + threadIdx.x) * 8;
  size_t row = idx >> 11;
  size_t col = idx & 2047;
  const float* src = (col < 1024) ? (x  + row * 1024 + col)
                                  : (hp + row * 1024 + (col - 1024));
  float4 v0 = *(const float4*)(src);
  float4 v1 = *(const float4*)(src + 4);
  ushort o[8] __attribute__((aligned(16)));
  o[0] = f2bf(v0.x); o[1] = f2bf(v0.y); o[2] = f2bf(v0.z); o[3] = f2bf(v0.w);
  o[4] = f2bf(v1.x); o[5] = f2bf(v1.y); o[6] = f2bf(v1.z); o[7] = f2bf(v1.w);
  *(uint4*)(Abf + idx) = *(uint4*)&o[0];
}

// ---------------------------------------------------------------------------
// Fused 4-gate GEMM + LSTM epilogue — WINDOW-PIPELINED structure.
//
// Block 256 rows x 256 fused cols, 8 waves = 4M x 2N, wave 64 x 128,
// acc[4 mf][8 j] (j = 2*gate + ns). BK=32 -> dbuf 32 KiB (A 16K + W 16K),
// 2 dbufs = 64 KiB LDS.
//
// Key change vs r4-r12: fragments for tile t+1 are read DURING window t,
// while MFMA crunches tile t's fragments (loaded last window, registers).
// The reads and the MFMAs are data-independent -> compiler's counted lgkm
// lets MFMA issue immediately after the barrier while reads + stage loads
// trickle in on the LDS/VMEM pipes. No sched_barriers (m141 lesson).
//
// Window w (tiles numbered = windows): 
//   RDSET(set[(w+1)&1] <- buf[(w+1)&1])   12 ds_read_b128  (tile w+1)
//   STAGE(tile (w+2)&63 -> buf[w&1])      4 gload_lds16
//   MFALL(set[w&1])                       32 MFMA
//   lgkmcnt(0)  (this wave's reads retired -> WAR guard at barrier)
//   vmcnt(0)    (this window's stages landed -> RAW guard)
//   s_barrier
// Ledger: WAR: buf[w&1] (tile w) reads retired by lgkmcnt(0)@BAR(w-1) in
//   ALL waves; stage issues after BAR(w-1). RAW: tile w+2 staged in window
//   w, landed by vmcnt(0)@BAR(w), first read in window w+1. Frag sets
//   alternate (static names). Prologue: stage t0,t1; vmcnt(0); BAR;
//   read F(0); lgkmcnt(0); BAR  (extra barrier so window 0's stage into
//   buf0 cannot race prologue reads of buf0). Tail window 63 reads wrapped
//   dead data (never consumed).
//
// Swizzle (r12-verified, 0 conflicts): 16B slot sl holds k-group
// sl ^ ((row>>1)&3); inverse on global source, folded into read base.
// mf/gate/ns deltas are +16n rows -> swizzle-invariant immediates.
// ---------------------------------------------------------------------------
__global__ __launch_bounds__(512, 2) void lstm_fused_kernel(
    const float* __restrict__ Cp, const ushort* __restrict__ Wt,
    const ushort* __restrict__ Abf,
    const float* __restrict__ bf_, const float* __restrict__ bi_,
    const float* __restrict__ bo_, const float* __restrict__ bc_,
    float* __restrict__ out) {
  __shared__ char lds[2 * DB2];   // 64 KiB

  const int bid = blockIdx.x;
  const int wg  = (bid & 7) * 64 + (bid >> 3);   // bijective, 512 % 8 == 0
  const int b0  = (wg >> 4) * BM;                // 32 M-tiles
  const int n0g = (wg & 15) * 64;                // 16 N-tiles (64 cols/gate)

  const int tid = threadIdx.x;
  const int ln  = tid & 63;
  const int wv  = tid >> 6;
  const int wm  = wv >> 1, wn = wv & 1;

  floatx4 acc[4][8];
#pragma unroll
  for (int m = 0; m < 4; ++m)
#pragma unroll
    for (int j = 0; j < 8; ++j) acc[m][j] = {0.f, 0.f, 0.f, 0.f};

  // ---- read bases (slot swizzle folded; all frag deltas immediate) ----
  const int q  = ((ln & 15) >> 1) & 3;
  const int sx = ((ln >> 4) ^ q) << 4;
  const int aB = (wm * 64 + (ln & 15)) * 64 + sx;          // + mf*1024
  const int bB = WOF + (wn * 32 + (ln & 15)) * 64 + sx;    // + g*4096 + ns*1024

  // ---- stage constants ----
  // slot s = i*512 + tid: row = i*128 + (tid>>2), sl = tid&3,
  // kg = sl ^ ((row>>1)&3) = (tid&3) ^ ((tid>>3)&3).
  const unsigned kg = ((unsigned)(tid & 3)) ^ ((unsigned)(tid >> 3) & 3);
  const char* AbfB = (const char*)Abf;
  const char* WtB  = (const char*)Wt;
  unsigned aoff[2], woff[2];
#pragma unroll
  for (int i = 0; i < 2; ++i) {
    int row = i * 128 + (tid >> 2);
    aoff[i] = (unsigned)(b0 + row) * 4096u + kg * 16u;
    int gate = row >> 6, nloc = row & 63;
    woff[i] = (unsigned)(gate * 1024 + n0g + nloc) * 4096u + kg * 16u;
  }
  const int dst0 = wv * 1024;        // wave-uniform LDS dest (lane adds 16)

#define STAGE(db, ktb)                                                        \
  do {                                                                        \
    gload_lds16(AbfB + (aoff[0] + (unsigned)(ktb)), lds + (db) + dst0);       \
    gload_lds16(AbfB + (aoff[1] + (unsigned)(ktb)), lds + (db) + 8192 + dst0);\
    gload_lds16(WtB  + (woff[0] + (unsigned)(ktb)), lds + (db) + WOF + dst0); \
    gload_lds16(WtB  + (woff[1] + (unsigned)(ktb)), lds + (db) + WOF + 8192 + dst0);\
  } while (0)

  short8 aFA[4], bFA[8];    // set A
  short8 aFB[4], bFB[8];    // set B
#define RDSET(AF, BF, db)                                                     \
  do {                                                                        \
    _Pragma("unroll")                                                         \
    for (int mf_ = 0; mf_ < 4; ++mf_)                                         \
      AF[mf_] = *(const short8*)(lds + (db) + aB + mf_ * 1024);               \
    _Pragma("unroll")                                                         \
    for (int j_ = 0; j_ < 8; ++j_)                                            \
      BF[j_] = *(const short8*)(lds + (db) + bB + (j_ >> 1) * 4096 +          \
                                (j_ & 1) * 1024);                             \
  } while (0)
#define MFALL(AF, BF)                                                         \
  do {                                                                        \
    __builtin_amdgcn_s_setprio(1);                                            \
    _Pragma("unroll")                                                         \
    for (int mf_ = 0; mf_ < 4; ++mf_)                                         \
      _Pragma("unroll")                                                       \
      for (int j_ = 0; j_ < 8; ++j_)                                          \
        acc[mf_][j_] = __builtin_amdgcn_mfma_f32_16x16x32_bf16(               \
            AF[mf_], BF[j_], acc[mf_][j_], 0, 0, 0);                          \
    __builtin_amdgcn_s_setprio(0);                                            \
  } while (0)
#define BAR    __builtin_amdgcn_s_barrier()
#define LGKM0  asm volatile("s_waitcnt lgkmcnt(0)" ::: "memory")
#define VMC0   asm volatile("s_waitcnt vmcnt(0)" ::: "memory")

  // ---- prologue: tiles 0,1 -> bufs 0,1; read F(0) safely ----
  STAGE(0, 0);
  STAGE(DB2, 64);          // tile 1, kt byte = 1*64
  VMC0; BAR;
  RDSET(aFA, bFA, 0);      // F(0) -> set A
  LGKM0; BAR;              // all waves' buf0 reads retired before window 0

#pragma unroll 1
  for (int it = 0; it < NKT / 2; ++it) {
    // window w = 2it (even): read F(w+1) from buf1 -> set B;
    //   stage tile (w+2)&63 -> buf0; MFMA set A (tile w)
    {
      const int ktb = (((2 * it + 2) & 63)) * 64;
      RDSET(aFB, bFB, DB2);
      STAGE(0, ktb);
      MFALL(aFA, bFA);
      LGKM0; VMC0; BAR;
    }
    // window w = 2it+1 (odd): read F(w+1) from buf0 -> set A;
    //   stage tile (w+2)&63 -> buf1; MFMA set B (tile w)
    {
      const int ktb = (((2 * it + 3) & 63)) * 64;
      RDSET(aFA, bFA, 0);
      STAGE(DB2, ktb);
      MFALL(aFB, bFB);
      LGKM0; VMC0; BAR;
    }
  }

  // ---- epilogue: gate g at acc[mf][2g+ns]; same lane/reg across gates ----
  const int colq = ln & 15;
  const int rq   = ln >> 4;
  float* outh = out;
  float* outC = out + (size_t)B_SZ * H_SZ;
#pragma unroll
  for (int mf = 0; mf < 4; ++mf) {
#pragma unroll
    for (int ns = 0; ns < 2; ++ns) {
      int n = n0g + wn * 32 + ns * 16 + colq;
      float vbf = bf_[n], vbi = bi_[n], vbo = bo_[n], vbc = bc_[n];
#pragma unroll
      for (int r = 0; r < 4; ++r) {
        int row = b0 + wm * 64 + mf * 16 + rq * 4 + r;
        float fg = sigmoidf_(acc[mf][0 + ns][r] + vbf);
        float ig = sigmoidf_(acc[mf][2 + ns][r] + vbi);
        float og = sigmoidf_(acc[mf][4 + ns][r] + vbo);
        float cg = tanhf_  (acc[mf][6 + ns][r] + vbc);
        float cp = Cp[(size_t)row * H_SZ + n];
        float Ct = fg * cp + ig * cg;
        float ht = og * tanhf_(Ct);
        outh[(size_t)row * H_SZ + n] = ht;
        outC[(size_t)row * H_SZ + n] = Ct;
      }
    }
  }
#undef STAGE
#undef RDSET
#undef MFALL
#undef BAR
#undef LGKM0
#undef VMC0
}

extern "C" void kernel_launch(void* const* d_in, const int* in_sizes, int n_in,
                              void* d_out, int out_size, void* d_ws, size_t ws_size,
                              hipStream_t stream) {
  const float* x  = (const float*)d_in[0];
  const float* hp = (const float*)d_in[1];
  const float* Cp = (const float*)d_in[2];
  const float* Wf = (const float*)d_in[3];
  const float* bf = (const float*)d_in[4];
  const float* Wi = (const float*)d_in[5];
  const float* bi = (const float*)d_in[6];
  const float* Wc = (const float*)d_in[7];
  const float* bc = (const float*)d_in[8];
  const float* Wo = (const float*)d_in[9];
  const float* bo = (const float*)d_in[10];

  ushort* Wt  = (ushort*)d_ws;                           // 16 MiB
  ushort* Abf = (ushort*)((char*)d_ws + (16u << 20));    // 32 MiB

  dim3 gridT(16, 32, 4);
  convert_w_kernel<<<gridT, 256, 0, stream>>>(Wf, Wi, Wo, Wc, Wt);
  convert_a_kernel<<<8192, 256, 0, stream>>>(x, hp, Abf);

  lstm_fused_kernel<<<512, 512, 0, stream>>>(Cp, Wt, Abf,
                                             bf, bi, bo, bc, (float*)d_out);
}